// Round 4
// baseline (285.900 us; speedup 1.0000x reference)
//
#include <hip/hip_runtime.h>
#include <hip/hip_bf16.h>

#define BB 8
#define TT 2048
#define CC 1024
#define HH 64
#define NSPLIT 8

typedef __attribute__((ext_vector_type(8)))  short bf16x8;
typedef __attribute__((ext_vector_type(4)))  float f32x4;
typedef __attribute__((ext_vector_type(16))) float f32x16;
typedef __attribute__((ext_vector_type(8)))  unsigned short us8;
typedef __attribute__((ext_vector_type(4)))  unsigned short us4;
typedef unsigned int u32;

static __device__ __forceinline__ unsigned short f2bf(float f) {
    union { float f; unsigned int u; } v; v.f = f;
    unsigned int u = v.u;
    return (unsigned short)((u + 0x7FFFu + ((u >> 16) & 1u)) >> 16);  // RNE
}
static __device__ __forceinline__ float bf2f(unsigned short s) {
    union { u32 u; float f; } v; v.u = ((u32)s) << 16; return v.f;
}

// ---------------------------------------------------------------------------
// Kernel 0: W [C][H] fp32 -> Wt [3][H][C] bf16 (transposed), fold log2(e)/8
// into Wq. ROUND-4: also zeroes the attn completion counters (256 ints) so
// the fused attn+norm epilogue starts clean every iteration (no extra API).
// ---------------------------------------------------------------------------
__global__ __launch_bounds__(256) void prep_weights(
        const float* __restrict__ Wq, const float* __restrict__ Wk,
        const float* __restrict__ Wv, unsigned short* __restrict__ Wt,
        int* __restrict__ cnt) {
    __shared__ float tile[64][65];
    int w  = blockIdx.x >> 4;       // 0..2
    int c0 = (blockIdx.x & 15) * 64;
    const float* W = (w == 0) ? Wq : (w == 1) ? Wk : Wv;
    int li = threadIdx.x;
    if (blockIdx.x == 0) cnt[li] = 0;          // 256 = BB*32 counters
    {
        int c = li >> 2, h4 = (li & 3) * 16;
        const float* src = W + (size_t)(c0 + c) * HH + h4;
        #pragma unroll
        for (int i = 0; i < 4; ++i) {
            float4 v4 = *(const float4*)(src + i * 4);
            tile[c][h4 + i*4 + 0] = v4.x; tile[c][h4 + i*4 + 1] = v4.y;
            tile[c][h4 + i*4 + 2] = v4.z; tile[c][h4 + i*4 + 3] = v4.w;
        }
    }
    __syncthreads();
    float scale = (w == 0) ? 0.1803368802f : 1.0f;   // log2(e)/sqrt(64)
    int h = li >> 2, cg = (li & 3) * 16;
    unsigned short* dst = Wt + (size_t)w * HH * CC + (size_t)h * CC + c0 + cg;
    #pragma unroll
    for (int i = 0; i < 16; ++i) dst[i] = f2bf(tile[cg + i][h] * scale);
}

// ---------------------------------------------------------------------------
// Kernel 1: fused QKV projection, full-K. ROUND-4 CHANGE: T4 counted-vmcnt.
// __syncthreads() forced vmcnt(0) -> drained the just-issued W prefetch every
// iter (fatal at 1 block/CU: no co-resident block to cover the stall).
// Now: s_waitcnt vmcnt(2) (in-order VMEM retirement => exactly drains
// stageW(kc), leaves the 2 X-prefetch loads in flight) + lgkmcnt(0) (my
// ds_writes visible) + raw s_barrier. Prefetch gll stays in flight ACROSS
// the barrier; each wave verifies its own loads pre-barrier (m201 pattern).
// ---------------------------------------------------------------------------
__global__ __launch_bounds__(512, 4) void proj_qkv(
        const float* __restrict__ x, const unsigned short* __restrict__ Wt,
        unsigned short* __restrict__ qws, unsigned short* __restrict__ kws,
        unsigned short* __restrict__ vws) {
    __shared__ unsigned short Xs[2][64 * 64];    // 8 KB each
    __shared__ unsigned short Ws[2][192 * 64];   // 24 KB each
    int tid = threadIdx.x;
    int wv = tid >> 6, lane = tid & 63;
    int quad = (lane >> 4) & 3, lq = lane & 15;
    int mg = wv >> 2, ng = wv & 3;
    int r0 = blockIdx.x * 64;

    // X staging: all 512 threads, 8 consecutive fp32 each (64 rows x 64 cols)
    int xr = tid >> 3, xg = tid & 7;
    const float* xsrc = x + (size_t)(r0 + xr) * CC + xg * 8;
    int xdst = xr * 64 + ((xg ^ (xr & 7)) * 8);
    float4 xa[2], xb[2];                         // 2-deep prefetch sets

    f32x4 acc[2][3];
    #pragma unroll
    for (int mt = 0; mt < 2; ++mt)
        #pragma unroll
        for (int nt = 0; nt < 3; ++nt)
            #pragma unroll
            for (int i = 0; i < 4; ++i) acc[mt][nt][i] = 0.0f;

    auto stageW = [&](int buf, int kc) {
        #pragma unroll
        for (int i = 0; i < 3; ++i) {
            int fp = tid + i * 512;            // 0..1535
            int r = fp >> 3, pb = fp & 7, g = pb ^ (r & 7);
            const u32 __attribute__((address_space(1)))* gsrc =
                (const u32 __attribute__((address_space(1)))*)
                    (Wt + (size_t)r * CC + kc * 64 + g * 8);
            u32 __attribute__((address_space(3)))* ldst =
                (u32 __attribute__((address_space(3)))*)(&Ws[buf][fp * 8]);
            __builtin_amdgcn_global_load_lds(gsrc, ldst, 16, 0, 0);
        }
    };
    auto loadX = [&](int set, int kc) {
        xa[set] = *(const float4*)(xsrc + kc * 64);
        xb[set] = *(const float4*)(xsrc + kc * 64 + 4);
    };
    auto writeX = [&](int set, int buf) {
        unsigned short h[8];
        h[0]=f2bf(xa[set].x); h[1]=f2bf(xa[set].y);
        h[2]=f2bf(xa[set].z); h[3]=f2bf(xa[set].w);
        h[4]=f2bf(xb[set].x); h[5]=f2bf(xb[set].y);
        h[6]=f2bf(xb[set].z); h[7]=f2bf(xb[set].w);
        *(us8*)&Xs[buf][xdst] = *(const us8*)h;
    };

    // prologue: W first (so the steady-state vmcnt(2) count holds at kc=0),
    // then X sets 0,1; writeX(0) forces the compiler's own vmcnt wait that
    // also drains stageW(0).
    stageW(0, 0);
    loadX(0, 0); loadX(1, 1);
    writeX(0, 0);

    for (int kc = 0; kc < 16; ++kc) {
        int cur = kc & 1;
        // counted wait: drain my stageW(kc) (+ ds_writes); keep X pair in flight
        if (kc < 15) asm volatile("s_waitcnt vmcnt(2) lgkmcnt(0)" ::: "memory");
        else         asm volatile("s_waitcnt vmcnt(0) lgkmcnt(0)" ::: "memory");
        __builtin_amdgcn_sched_barrier(0);
        __builtin_amdgcn_s_barrier();        // all waves' buf[cur] now valid
        if (kc < 15) stageW(1 - cur, kc + 1);   // buf[1-cur]: reads finished kc-1
        if (kc < 14) loadX(kc & 1, kc + 2);     // refill freed X set
        #pragma unroll
        for (int ks = 0; ks < 2; ++ks) {
            int g = ks * 4 + quad;
            bf16x8 a[2], b[3];
            #pragma unroll
            for (int mt = 0; mt < 2; ++mt) {
                int arow = mg * 32 + mt * 16 + lq;
                a[mt] = *(const bf16x8*)&Xs[cur][arow * 64 + (g ^ (lq & 7)) * 8];
            }
            #pragma unroll
            for (int nt = 0; nt < 3; ++nt) {
                int brow = ng * 48 + nt * 16 + lq;
                b[nt] = *(const bf16x8*)&Ws[cur][brow * 64 + (g ^ (lq & 7)) * 8];
            }
            #pragma unroll
            for (int mt = 0; mt < 2; ++mt)
                #pragma unroll
                for (int nt = 0; nt < 3; ++nt)
                    acc[mt][nt] = __builtin_amdgcn_mfma_f32_16x16x32_bf16(
                        a[mt], b[nt], acc[mt][nt], 0, 0, 0);
        }
        if (kc < 15) writeX((kc + 1) & 1, 1 - cur);  // X[kc+1]
    }

    // epilogue: direct q|k|v writes (wave-uniform column buckets).
    int bidx = r0 >> 11;                       // batch
    int t0base = r0 & (TT - 1);
    #pragma unroll
    for (int mt = 0; mt < 2; ++mt) {
        #pragma unroll
        for (int nt = 0; nt < 3; ++nt) {
            int gcol = ng * 48 + nt * 16 + lq;
            int rloc = mg * 32 + mt * 16 + quad * 4;      // + i
            if (gcol < 64) {
                #pragma unroll
                for (int i = 0; i < 4; ++i)
                    qws[(size_t)(r0 + rloc + i) * HH + gcol] =
                        f2bf(acc[mt][nt][i]);
            } else if (gcol < 128) {
                #pragma unroll
                for (int i = 0; i < 4; ++i)
                    kws[(size_t)(r0 + rloc + i) * HH + (gcol - 64)] =
                        f2bf(acc[mt][nt][i]);
            } else {
                // v transposed: [b][h][t], 4 consecutive t -> one 8B store
                unsigned short o[4];
                #pragma unroll
                for (int i = 0; i < 4; ++i) o[i] = f2bf(acc[mt][nt][i]);
                *(us4*)(vws + ((size_t)bidx * HH + (gcol - 128)) * TT
                            + t0base + rloc) = *(const us4*)o;
            }
        }
    }
}

// ---------------------------------------------------------------------------
// Kernel 2: causal attention + FUSED normalization (ROUND-4). Each (ti,s,b)
// block stores its split partials (Op,Lp), fences device-wide, then bumps a
// per-(b,ti) counter; the LAST finisher re-fences and computes the
// deterministic fixed-order split sum -> writes `out` directly. Removes the
// norm_out launch boundary and overlaps normalization with attn's tail.
// ---------------------------------------------------------------------------
__global__ __launch_bounds__(128, 3) void attn(
        const unsigned short* __restrict__ qws,
        const unsigned short* __restrict__ kws,
        const unsigned short* __restrict__ vws,
        unsigned short* __restrict__ Op, float* __restrict__ Lp,
        float* __restrict__ out, int* __restrict__ cnt) {
    __shared__ unsigned short Kt[32][72];   // [key][h]
    __shared__ unsigned short Vt[64][40];   // [h][key]
    __shared__ unsigned short Ps[64][40];   // [q][key], rows wave-private
    __shared__ int lastflag;
    int ti = blockIdx.x;            // 64-row q tile, 0..31
    int s  = blockIdx.y;            // kv split 0..NSPLIT-1
    int b  = blockIdx.z;
    int last = 2 * ti + 1;          // last 32-key chunk index for this tile
    if (s > last) return;
    int tid = threadIdx.x, wv = tid >> 6, lane = tid & 63;
    int half = lane >> 5, l31 = lane & 31;

    bf16x8 qf[4];
    {
        const unsigned short* qp =
            qws + ((size_t)b * TT + ti * 64 + wv * 32 + l31) * HH + half * 8;
        #pragma unroll
        for (int ks = 0; ks < 4; ++ks) qf[ks] = *(const bf16x8*)(qp + ks * 16);
    }
    f32x16 O0, O1, Lc;
    #pragma unroll
    for (int i = 0; i < 16; ++i) { O0[i] = 0.f; O1[i] = 0.f; Lc[i] = 0.f; }
    bf16x8 ones;
    #pragma unroll
    for (int i = 0; i < 8; ++i) ones[i] = (short)0x3F80;

    // staging addresses (invariant parts)
    int kr = tid >> 3, kg = tid & 7;          // K: rows 0..15 (+16), col group
    int vh = tid >> 2, vkb = tid & 3;         // V: h 0..31 (+32), key group
    const unsigned short* ksrc0 = kws + ((size_t)b * TT + kr) * HH + kg * 8;
    const unsigned short* vsrc0 = vws + ((size_t)b * HH + vh) * TT + vkb * 8;

    us8 rk[2], rv[2];                          // T14 prefetch registers
    auto loadKV = [&](int jc) {
        rk[0] = *(const us8*)(ksrc0 + (size_t)(jc * 32) * HH);
        rk[1] = *(const us8*)(ksrc0 + (size_t)(jc * 32 + 16) * HH);
        rv[0] = *(const us8*)(vsrc0 + jc * 32);
        rv[1] = *(const us8*)(vsrc0 + (size_t)32 * TT + jc * 32);
    };
    auto writeKV = [&]() {
        *(us8*)&Kt[kr][kg * 8]       = rk[0];
        *(us8*)&Kt[kr + 16][kg * 8]  = rk[1];
        *(us8*)&Vt[vh][vkb * 8]      = rv[0];
        *(us8*)&Vt[vh + 32][vkb * 8] = rv[1];
    };

    loadKV(s);                                 // prologue prefetch
    for (int jc = s; jc <= last; jc += NSPLIT) {
        __syncthreads();   // prior iter's K/V reads done before restage
        writeKV();
        if (jc + NSPLIT <= last) loadKV(jc + NSPLIT);   // hide under compute
        __syncthreads();
        f32x16 S;
        #pragma unroll
        for (int i = 0; i < 16; ++i) S[i] = 0.f;
        #pragma unroll
        for (int ks = 0; ks < 4; ++ks) {
            bf16x8 kf = *(const bf16x8*)&Kt[l31][ks * 16 + half * 8];
            S = __builtin_amdgcn_mfma_f32_32x32x16_bf16(qf[ks], kf, S, 0, 0, 0);
        }
        bool diag = (jc >= 2 * ti + wv);   // chunk can touch this wave's diagonal
        #pragma unroll
        for (int r = 0; r < 16; ++r) {
            int pat = (r & 3) + 8 * (r >> 2) + 4 * half;    // local q row in wave
            float p = __builtin_amdgcn_exp2f(S[r]);
            if (diag && jc * 32 + l31 > ti * 64 + wv * 32 + pat) p = 0.0f;
            Ps[wv * 32 + pat][l31] = f2bf(p);
        }
        // no __syncthreads: each wave reads only its own 32 Ps rows
        #pragma unroll
        for (int ks = 0; ks < 2; ++ks) {
            bf16x8 pa  = *(const bf16x8*)&Ps[wv * 32 + l31][ks * 16 + half * 8];
            bf16x8 vf0 = *(const bf16x8*)&Vt[l31][ks * 16 + half * 8];
            bf16x8 vf1 = *(const bf16x8*)&Vt[32 + l31][ks * 16 + half * 8];
            O0 = __builtin_amdgcn_mfma_f32_32x32x16_bf16(pa, vf0, O0, 0, 0, 0);
            O1 = __builtin_amdgcn_mfma_f32_32x32x16_bf16(pa, vf1, O1, 0, 0, 0);
            Lc = __builtin_amdgcn_mfma_f32_32x32x16_bf16(pa, ones, Lc, 0, 0, 0);
        }
    }
    // deterministic per-split partial store (bf16)
    unsigned short* Ob =
        Op + (((size_t)s * BB + b) * TT + ti * 64 + wv * 32) * HH;
    #pragma unroll
    for (int r = 0; r < 16; ++r) {
        int pat = (r & 3) + 8 * (r >> 2) + 4 * half;
        Ob[(size_t)pat * HH + l31]      = f2bf(O0[r]);
        Ob[(size_t)pat * HH + 32 + l31] = f2bf(O1[r]);
    }
    if (l31 == 0) {
        #pragma unroll
        for (int r = 0; r < 16; ++r) {
            int pat = (r & 3) + 8 * (r >> 2) + 4 * half;
            Lp[((size_t)s * BB + b) * TT + ti * 64 + wv * 32 + pat] = Lc[r];
        }
    }

    // ---- fused normalization: last finisher of (b,ti) sums the splits ----
    int ns = min(2 * ti + 2, NSPLIT);
    __threadfence();                 // release my Op/Lp stores device-wide
    __syncthreads();                 // all threads' stores fenced
    if (tid == 0) {
        int prev = atomicAdd(&cnt[b * 32 + ti], 1);
        lastflag = (prev == ns - 1) ? 1 : 0;
    }
    __syncthreads();
    if (lastflag) {
        __threadfence();             // acquire: other blocks' stores visible
        int lr0 = tid >> 2, hb = (tid & 3) * 16;   // 4 threads/row, 32 rows/pass
        #pragma unroll
        for (int hf = 0; hf < 2; ++hf) {
            size_t g = (size_t)b * TT + ti * 64 + hf * 32 + lr0;
            float a[16];
            #pragma unroll
            for (int j = 0; j < 16; ++j) a[j] = 0.f;
            float Ls = 0.f;
            for (int s2 = 0; s2 < ns; ++s2) {      // fixed order: deterministic
                const unsigned short* base =
                    Op + ((size_t)s2 * BB * TT + g) * HH + hb;
                us8 u0 = *(const us8*)base;
                us8 u1 = *(const us8*)(base + 8);
                #pragma unroll
                for (int j = 0; j < 8; ++j) {
                    a[j] += bf2f(u0[j]); a[8 + j] += bf2f(u1[j]);
                }
                Ls += Lp[(size_t)s2 * BB * TT + g];
            }
            float inv = 1.0f / Ls;
            float* ob = out + g * HH + hb;
            #pragma unroll
            for (int q = 0; q < 4; ++q)
                ((float4*)ob)[q] = make_float4(a[q*4] * inv, a[q*4+1] * inv,
                                               a[q*4+2] * inv, a[q*4+3] * inv);
        }
    }
}

// ---------------------------------------------------------------------------
extern "C" void kernel_launch(void* const* d_in, const int* in_sizes, int n_in,
                              void* d_out, int out_size, void* d_ws, size_t ws_size,
                              hipStream_t stream) {
    (void)in_sizes; (void)n_in; (void)out_size; (void)ws_size;
    const float* x  = (const float*)d_in[0];
    const float* Wq = (const float*)d_in[1];
    const float* Wk = (const float*)d_in[2];
    const float* Wv = (const float*)d_in[3];
    float* out = (float*)d_out;

    char* ws = (char*)d_ws;
    unsigned short* Wt  = (unsigned short*)ws;                          // 384 KB
    unsigned short* qws = (unsigned short*)(ws + (1u << 19));           // 2 MB
    unsigned short* kws = (unsigned short*)(ws + (1u << 19) + (1u << 21));
    unsigned short* vws = (unsigned short*)(ws + (1u << 19) + (2u << 21));
    unsigned short* Op  = (unsigned short*)(ws + (1u << 19) + (3u << 21)); // 16 MB bf16
    float*          Lp  = (float*)(ws + (1u << 19) + (3u << 21) + (1u << 24)); // 512 KB
    int*            cnt = (int*)(ws + (1u << 19) + (3u << 21) + (1u << 24)
                                    + (1u << 19));                         // 1 KB

    prep_weights<<<48, 256, 0, stream>>>(Wq, Wk, Wv, Wt, cnt);
    proj_qkv<<<256, 512, 0, stream>>>(x, Wt, qws, kws, vws);
    attn<<<dim3(32, NSPLIT, 8), 128, 0, stream>>>(qws, kws, vws, Op, Lp, out, cnt);
}

// Round 5
// 134.299 us; speedup vs baseline: 2.1288x; 2.1288x over previous
//
#include <hip/hip_runtime.h>
#include <hip/hip_bf16.h>

#define BB 8
#define TT 2048
#define CC 1024
#define HH 64
#define NSPLIT 8

typedef __attribute__((ext_vector_type(8)))  short bf16x8;
typedef __attribute__((ext_vector_type(4)))  float f32x4;
typedef __attribute__((ext_vector_type(16))) float f32x16;
typedef __attribute__((ext_vector_type(8)))  unsigned short us8;
typedef __attribute__((ext_vector_type(4)))  unsigned short us4;
typedef unsigned int u32;

static __device__ __forceinline__ unsigned short f2bf(float f) {
    union { float f; unsigned int u; } v; v.f = f;
    unsigned int u = v.u;
    return (unsigned short)((u + 0x7FFFu + ((u >> 16) & 1u)) >> 16);  // RNE
}
static __device__ __forceinline__ float bf2f(unsigned short s) {
    union { u32 u; float f; } v; v.u = ((u32)s) << 16; return v.f;
}

// ---------------------------------------------------------------------------
// Kernel 0: W [C][H] fp32 -> Wt [3][H][C] bf16 (transposed), fold log2(e)/8
// into Wq so QK^T scores come out in the log2 domain. (round-3 version)
// ---------------------------------------------------------------------------
__global__ __launch_bounds__(256) void prep_weights(
        const float* __restrict__ Wq, const float* __restrict__ Wk,
        const float* __restrict__ Wv, unsigned short* __restrict__ Wt) {
    __shared__ float tile[64][65];
    int w  = blockIdx.x >> 4;       // 0..2
    int c0 = (blockIdx.x & 15) * 64;
    const float* W = (w == 0) ? Wq : (w == 1) ? Wk : Wv;
    int li = threadIdx.x;
    {
        int c = li >> 2, h4 = (li & 3) * 16;
        const float* src = W + (size_t)(c0 + c) * HH + h4;
        #pragma unroll
        for (int i = 0; i < 4; ++i) {
            float4 v4 = *(const float4*)(src + i * 4);
            tile[c][h4 + i*4 + 0] = v4.x; tile[c][h4 + i*4 + 1] = v4.y;
            tile[c][h4 + i*4 + 2] = v4.z; tile[c][h4 + i*4 + 3] = v4.w;
        }
    }
    __syncthreads();
    float scale = (w == 0) ? 0.1803368802f : 1.0f;   // log2(e)/sqrt(64)
    int h = li >> 2, cg = (li & 3) * 16;
    unsigned short* dst = Wt + (size_t)w * HH * CC + (size_t)h * CC + c0 + cg;
    #pragma unroll
    for (int i = 0; i < 16; ++i) dst[i] = f2bf(tile[cg + i][h] * scale);
}

// ---------------------------------------------------------------------------
// Kernel 1: fused QKV projection, full-K, T4 counted-vmcnt (round-4 version,
// kept). s_waitcnt vmcnt(2) drains exactly stageW(kc) (in-order VMEM
// retirement; the 2 newest outstanding ops are the X float4 pair), keeping
// the X prefetch in flight; W prefetch for kc+1 issues after the barrier and
// stays in flight across the next barrier. No full vmcnt(0) drain per iter.
// ---------------------------------------------------------------------------
__global__ __launch_bounds__(512, 4) void proj_qkv(
        const float* __restrict__ x, const unsigned short* __restrict__ Wt,
        unsigned short* __restrict__ qws, unsigned short* __restrict__ kws,
        unsigned short* __restrict__ vws) {
    __shared__ unsigned short Xs[2][64 * 64];    // 8 KB each
    __shared__ unsigned short Ws[2][192 * 64];   // 24 KB each
    int tid = threadIdx.x;
    int wv = tid >> 6, lane = tid & 63;
    int quad = (lane >> 4) & 3, lq = lane & 15;
    int mg = wv >> 2, ng = wv & 3;
    int r0 = blockIdx.x * 64;

    // X staging: all 512 threads, 8 consecutive fp32 each (64 rows x 64 cols)
    int xr = tid >> 3, xg = tid & 7;
    const float* xsrc = x + (size_t)(r0 + xr) * CC + xg * 8;
    int xdst = xr * 64 + ((xg ^ (xr & 7)) * 8);
    float4 xa[2], xb[2];                         // 2-deep prefetch sets

    f32x4 acc[2][3];
    #pragma unroll
    for (int mt = 0; mt < 2; ++mt)
        #pragma unroll
        for (int nt = 0; nt < 3; ++nt)
            #pragma unroll
            for (int i = 0; i < 4; ++i) acc[mt][nt][i] = 0.0f;

    auto stageW = [&](int buf, int kc) {
        #pragma unroll
        for (int i = 0; i < 3; ++i) {
            int fp = tid + i * 512;            // 0..1535
            int r = fp >> 3, pb = fp & 7, g = pb ^ (r & 7);
            const u32 __attribute__((address_space(1)))* gsrc =
                (const u32 __attribute__((address_space(1)))*)
                    (Wt + (size_t)r * CC + kc * 64 + g * 8);
            u32 __attribute__((address_space(3)))* ldst =
                (u32 __attribute__((address_space(3)))*)(&Ws[buf][fp * 8]);
            __builtin_amdgcn_global_load_lds(gsrc, ldst, 16, 0, 0);
        }
    };
    auto loadX = [&](int set, int kc) {
        xa[set] = *(const float4*)(xsrc + kc * 64);
        xb[set] = *(const float4*)(xsrc + kc * 64 + 4);
    };
    auto writeX = [&](int set, int buf) {
        unsigned short h[8];
        h[0]=f2bf(xa[set].x); h[1]=f2bf(xa[set].y);
        h[2]=f2bf(xa[set].z); h[3]=f2bf(xa[set].w);
        h[4]=f2bf(xb[set].x); h[5]=f2bf(xb[set].y);
        h[6]=f2bf(xb[set].z); h[7]=f2bf(xb[set].w);
        *(us8*)&Xs[buf][xdst] = *(const us8*)h;
    };

    // prologue: W first (so the steady-state vmcnt(2) count holds at kc=0),
    // then X sets 0,1; writeX(0) forces the compiler's own vmcnt wait that
    // also drains stageW(0).
    stageW(0, 0);
    loadX(0, 0); loadX(1, 1);
    writeX(0, 0);

    for (int kc = 0; kc < 16; ++kc) {
        int cur = kc & 1;
        // counted wait: drain my stageW(kc) (+ ds_writes); keep X pair in flight
        if (kc < 15) asm volatile("s_waitcnt vmcnt(2) lgkmcnt(0)" ::: "memory");
        else         asm volatile("s_waitcnt vmcnt(0) lgkmcnt(0)" ::: "memory");
        __builtin_amdgcn_sched_barrier(0);
        __builtin_amdgcn_s_barrier();        // all waves' buf[cur] now valid
        if (kc < 15) stageW(1 - cur, kc + 1);   // buf[1-cur]: reads finished kc-1
        if (kc < 14) loadX(kc & 1, kc + 2);     // refill freed X set
        #pragma unroll
        for (int ks = 0; ks < 2; ++ks) {
            int g = ks * 4 + quad;
            bf16x8 a[2], b[3];
            #pragma unroll
            for (int mt = 0; mt < 2; ++mt) {
                int arow = mg * 32 + mt * 16 + lq;
                a[mt] = *(const bf16x8*)&Xs[cur][arow * 64 + (g ^ (lq & 7)) * 8];
            }
            #pragma unroll
            for (int nt = 0; nt < 3; ++nt) {
                int brow = ng * 48 + nt * 16 + lq;
                b[nt] = *(const bf16x8*)&Ws[cur][brow * 64 + (g ^ (lq & 7)) * 8];
            }
            #pragma unroll
            for (int mt = 0; mt < 2; ++mt)
                #pragma unroll
                for (int nt = 0; nt < 3; ++nt)
                    acc[mt][nt] = __builtin_amdgcn_mfma_f32_16x16x32_bf16(
                        a[mt], b[nt], acc[mt][nt], 0, 0, 0);
        }
        if (kc < 15) writeX((kc + 1) & 1, 1 - cur);  // X[kc+1]
    }

    // epilogue: direct q|k|v writes (wave-uniform column buckets).
    int bidx = r0 >> 11;                       // batch
    int t0base = r0 & (TT - 1);
    #pragma unroll
    for (int mt = 0; mt < 2; ++mt) {
        #pragma unroll
        for (int nt = 0; nt < 3; ++nt) {
            int gcol = ng * 48 + nt * 16 + lq;
            int rloc = mg * 32 + mt * 16 + quad * 4;      // + i
            if (gcol < 64) {
                #pragma unroll
                for (int i = 0; i < 4; ++i)
                    qws[(size_t)(r0 + rloc + i) * HH + gcol] =
                        f2bf(acc[mt][nt][i]);
            } else if (gcol < 128) {
                #pragma unroll
                for (int i = 0; i < 4; ++i)
                    kws[(size_t)(r0 + rloc + i) * HH + (gcol - 64)] =
                        f2bf(acc[mt][nt][i]);
            } else {
                // v transposed: [b][h][t], 4 consecutive t -> one 8B store
                unsigned short o[4];
                #pragma unroll
                for (int i = 0; i < 4; ++i) o[i] = f2bf(acc[mt][nt][i]);
                *(us4*)(vws + ((size_t)bidx * HH + (gcol - 128)) * TT
                            + t0base + rloc) = *(const us4*)o;
            }
        }
    }
}

// ---------------------------------------------------------------------------
// Kernel 2: causal attention — round-2 PASSED version (T14 async-STAGE),
// fence/atomic fusion REVERTED (round-4 post-mortem: device-scope
// __threadfence per block serialized the grid, attn 40 -> 187 us).
// ---------------------------------------------------------------------------
__global__ __launch_bounds__(128, 3) void attn(
        const unsigned short* __restrict__ qws,
        const unsigned short* __restrict__ kws,
        const unsigned short* __restrict__ vws,
        unsigned short* __restrict__ Op, float* __restrict__ Lp) {
    __shared__ unsigned short Kt[32][72];   // [key][h]
    __shared__ unsigned short Vt[64][40];   // [h][key]
    __shared__ unsigned short Ps[64][40];   // [q][key], rows wave-private
    int ti = blockIdx.x;            // 64-row q tile, 0..31
    int s  = blockIdx.y;            // kv split 0..NSPLIT-1
    int b  = blockIdx.z;
    int last = 2 * ti + 1;          // last 32-key chunk index for this tile
    if (s > last) return;
    int tid = threadIdx.x, wv = tid >> 6, lane = tid & 63;
    int half = lane >> 5, l31 = lane & 31;

    bf16x8 qf[4];
    {
        const unsigned short* qp =
            qws + ((size_t)b * TT + ti * 64 + wv * 32 + l31) * HH + half * 8;
        #pragma unroll
        for (int ks = 0; ks < 4; ++ks) qf[ks] = *(const bf16x8*)(qp + ks * 16);
    }
    f32x16 O0, O1, Lc;
    #pragma unroll
    for (int i = 0; i < 16; ++i) { O0[i] = 0.f; O1[i] = 0.f; Lc[i] = 0.f; }
    bf16x8 ones;
    #pragma unroll
    for (int i = 0; i < 8; ++i) ones[i] = (short)0x3F80;

    // staging addresses (invariant parts)
    int kr = tid >> 3, kg = tid & 7;          // K: rows 0..15 (+16), col group
    int vh = tid >> 2, vkb = tid & 3;         // V: h 0..31 (+32), key group
    const unsigned short* ksrc0 = kws + ((size_t)b * TT + kr) * HH + kg * 8;
    const unsigned short* vsrc0 = vws + ((size_t)b * HH + vh) * TT + vkb * 8;

    us8 rk[2], rv[2];                          // T14 prefetch registers
    auto loadKV = [&](int jc) {
        rk[0] = *(const us8*)(ksrc0 + (size_t)(jc * 32) * HH);
        rk[1] = *(const us8*)(ksrc0 + (size_t)(jc * 32 + 16) * HH);
        rv[0] = *(const us8*)(vsrc0 + jc * 32);
        rv[1] = *(const us8*)(vsrc0 + (size_t)32 * TT + jc * 32);
    };
    auto writeKV = [&]() {
        *(us8*)&Kt[kr][kg * 8]       = rk[0];
        *(us8*)&Kt[kr + 16][kg * 8]  = rk[1];
        *(us8*)&Vt[vh][vkb * 8]      = rv[0];
        *(us8*)&Vt[vh + 32][vkb * 8] = rv[1];
    };

    loadKV(s);                                 // prologue prefetch
    for (int jc = s; jc <= last; jc += NSPLIT) {
        __syncthreads();   // prior iter's K/V reads done before restage
        writeKV();
        if (jc + NSPLIT <= last) loadKV(jc + NSPLIT);   // hide under compute
        __syncthreads();
        f32x16 S;
        #pragma unroll
        for (int i = 0; i < 16; ++i) S[i] = 0.f;
        #pragma unroll
        for (int ks = 0; ks < 4; ++ks) {
            bf16x8 kf = *(const bf16x8*)&Kt[l31][ks * 16 + half * 8];
            S = __builtin_amdgcn_mfma_f32_32x32x16_bf16(qf[ks], kf, S, 0, 0, 0);
        }
        bool diag = (jc >= 2 * ti + wv);   // chunk can touch this wave's diagonal
        #pragma unroll
        for (int r = 0; r < 16; ++r) {
            int pat = (r & 3) + 8 * (r >> 2) + 4 * half;    // local q row in wave
            float p = __builtin_amdgcn_exp2f(S[r]);
            if (diag && jc * 32 + l31 > ti * 64 + wv * 32 + pat) p = 0.0f;
            Ps[wv * 32 + pat][l31] = f2bf(p);
        }
        // no __syncthreads: each wave reads only its own 32 Ps rows
        #pragma unroll
        for (int ks = 0; ks < 2; ++ks) {
            bf16x8 pa  = *(const bf16x8*)&Ps[wv * 32 + l31][ks * 16 + half * 8];
            bf16x8 vf0 = *(const bf16x8*)&Vt[l31][ks * 16 + half * 8];
            bf16x8 vf1 = *(const bf16x8*)&Vt[32 + l31][ks * 16 + half * 8];
            O0 = __builtin_amdgcn_mfma_f32_32x32x16_bf16(pa, vf0, O0, 0, 0, 0);
            O1 = __builtin_amdgcn_mfma_f32_32x32x16_bf16(pa, vf1, O1, 0, 0, 0);
            Lc = __builtin_amdgcn_mfma_f32_32x32x16_bf16(pa, ones, Lc, 0, 0, 0);
        }
    }
    // deterministic per-split partial store (bf16)
    unsigned short* Ob =
        Op + (((size_t)s * BB + b) * TT + ti * 64 + wv * 32) * HH;
    #pragma unroll
    for (int r = 0; r < 16; ++r) {
        int pat = (r & 3) + 8 * (r >> 2) + 4 * half;
        Ob[(size_t)pat * HH + l31]      = f2bf(O0[r]);
        Ob[(size_t)pat * HH + 32 + l31] = f2bf(O1[r]);
    }
    if (l31 == 0) {
        #pragma unroll
        for (int r = 0; r < 16; ++r) {
            int pat = (r & 3) + 8 * (r >> 2) + 4 * half;
            Lp[((size_t)s * BB + b) * TT + ti * 64 + wv * 32 + pat] = Lc[r];
        }
    }
}

// ---------------------------------------------------------------------------
// Kernel 3: out = (sum_s Op[s]) / (sum_s Lp[s]) — restored (round-3 version).
// ---------------------------------------------------------------------------
__global__ __launch_bounds__(256) void norm_out(
        const unsigned short* __restrict__ Op, const float* __restrict__ Lp,
        float* __restrict__ out) {
    int idx = blockIdx.x * 256 + threadIdx.x;     // 65536 total
    int g = idx >> 2;                             // global row b*T + t, <16384
    int hseg = (idx & 3) * 16;
    int ti = (g & (TT - 1)) >> 6;
    int ns = min(2 * ti + 2, NSPLIT);
    float a[16];
    #pragma unroll
    for (int j = 0; j < 16; ++j) a[j] = 0.f;
    float Ls = 0.f;
    for (int s = 0; s < ns; ++s) {
        const unsigned short* base =
            Op + ((size_t)s * BB * TT + g) * HH + hseg;
        us8 u0 = *(const us8*)base;
        us8 u1 = *(const us8*)(base + 8);
        #pragma unroll
        for (int j = 0; j < 8; ++j) { a[j] += bf2f(u0[j]); a[8 + j] += bf2f(u1[j]); }
        Ls += Lp[(size_t)s * BB * TT + g];
    }
    float inv = 1.0f / Ls;
    float* ob = out + (size_t)g * HH + hseg;
    #pragma unroll
    for (int q = 0; q < 4; ++q) {
        float4 v = make_float4(a[q*4] * inv, a[q*4+1] * inv,
                               a[q*4+2] * inv, a[q*4+3] * inv);
        ((float4*)ob)[q] = v;
    }
}

// ---------------------------------------------------------------------------
extern "C" void kernel_launch(void* const* d_in, const int* in_sizes, int n_in,
                              void* d_out, int out_size, void* d_ws, size_t ws_size,
                              hipStream_t stream) {
    (void)in_sizes; (void)n_in; (void)out_size; (void)ws_size;
    const float* x  = (const float*)d_in[0];
    const float* Wq = (const float*)d_in[1];
    const float* Wk = (const float*)d_in[2];
    const float* Wv = (const float*)d_in[3];
    float* out = (float*)d_out;

    char* ws = (char*)d_ws;
    unsigned short* Wt  = (unsigned short*)ws;                          // 384 KB
    unsigned short* qws = (unsigned short*)(ws + (1u << 19));           // 2 MB
    unsigned short* kws = (unsigned short*)(ws + (1u << 19) + (1u << 21));
    unsigned short* vws = (unsigned short*)(ws + (1u << 19) + (2u << 21));
    unsigned short* Op  = (unsigned short*)(ws + (1u << 19) + (3u << 21)); // 16 MB bf16
    float*          Lp  = (float*)(ws + (1u << 19) + (3u << 21) + (1u << 24)); // 512 KB

    prep_weights<<<48, 256, 0, stream>>>(Wq, Wk, Wv, Wt);
    proj_qkv<<<256, 512, 0, stream>>>(x, Wt, qws, kws, vws);
    attn<<<dim3(32, NSPLIT, 8), 128, 0, stream>>>(qws, kws, vws, Op, Lp);
    norm_out<<<256, 256, 0, stream>>>(Op, Lp, out);
}

// Round 6
// 131.356 us; speedup vs baseline: 2.1765x; 1.0224x over previous
//
#include <hip/hip_runtime.h>
#include <hip/hip_bf16.h>

#define BB 8
#define TT 2048
#define CC 1024
#define HH 64
#define NSPLIT 4

typedef __attribute__((ext_vector_type(8)))  short bf16x8;
typedef __attribute__((ext_vector_type(4)))  float f32x4;
typedef __attribute__((ext_vector_type(16))) float f32x16;
typedef __attribute__((ext_vector_type(8)))  unsigned short us8;
typedef __attribute__((ext_vector_type(4)))  unsigned short us4;
typedef unsigned int u32;

static __device__ __forceinline__ unsigned short f2bf(float f) {
    union { float f; unsigned int u; } v; v.f = f;
    unsigned int u = v.u;
    return (unsigned short)((u + 0x7FFFu + ((u >> 16) & 1u)) >> 16);  // RNE
}
static __device__ __forceinline__ float bf2f(unsigned short s) {
    union { u32 u; float f; } v; v.u = ((u32)s) << 16; return v.f;
}

// ---------------------------------------------------------------------------
// Kernel 0: W [C][H] fp32 -> Wt [3][H][C] bf16 (transposed), fold log2(e)/8
// into Wq so QK^T scores come out in the log2 domain. (unchanged)
// ---------------------------------------------------------------------------
__global__ __launch_bounds__(256) void prep_weights(
        const float* __restrict__ Wq, const float* __restrict__ Wk,
        const float* __restrict__ Wv, unsigned short* __restrict__ Wt) {
    __shared__ float tile[64][65];
    int w  = blockIdx.x >> 4;       // 0..2
    int c0 = (blockIdx.x & 15) * 64;
    const float* W = (w == 0) ? Wq : (w == 1) ? Wk : Wv;
    int li = threadIdx.x;
    {
        int c = li >> 2, h4 = (li & 3) * 16;
        const float* src = W + (size_t)(c0 + c) * HH + h4;
        #pragma unroll
        for (int i = 0; i < 4; ++i) {
            float4 v4 = *(const float4*)(src + i * 4);
            tile[c][h4 + i*4 + 0] = v4.x; tile[c][h4 + i*4 + 1] = v4.y;
            tile[c][h4 + i*4 + 2] = v4.z; tile[c][h4 + i*4 + 3] = v4.w;
        }
    }
    __syncthreads();
    float scale = (w == 0) ? 0.1803368802f : 1.0f;   // log2(e)/sqrt(64)
    int h = li >> 2, cg = (li & 3) * 16;
    unsigned short* dst = Wt + (size_t)w * HH * CC + (size_t)h * CC + c0 + cg;
    #pragma unroll
    for (int i = 0; i < 16; ++i) dst[i] = f2bf(tile[cg + i][h] * scale);
}

// ---------------------------------------------------------------------------
// Kernel 1: fused QKV projection, full-K, T4 counted-vmcnt (round-5 PASSED
// version, verbatim).
// ---------------------------------------------------------------------------
__global__ __launch_bounds__(512, 4) void proj_qkv(
        const float* __restrict__ x, const unsigned short* __restrict__ Wt,
        unsigned short* __restrict__ qws, unsigned short* __restrict__ kws,
        unsigned short* __restrict__ vws) {
    __shared__ unsigned short Xs[2][64 * 64];    // 8 KB each
    __shared__ unsigned short Ws[2][192 * 64];   // 24 KB each
    int tid = threadIdx.x;
    int wv = tid >> 6, lane = tid & 63;
    int quad = (lane >> 4) & 3, lq = lane & 15;
    int mg = wv >> 2, ng = wv & 3;
    int r0 = blockIdx.x * 64;

    int xr = tid >> 3, xg = tid & 7;
    const float* xsrc = x + (size_t)(r0 + xr) * CC + xg * 8;
    int xdst = xr * 64 + ((xg ^ (xr & 7)) * 8);
    float4 xa[2], xb[2];                         // 2-deep prefetch sets

    f32x4 acc[2][3];
    #pragma unroll
    for (int mt = 0; mt < 2; ++mt)
        #pragma unroll
        for (int nt = 0; nt < 3; ++nt)
            #pragma unroll
            for (int i = 0; i < 4; ++i) acc[mt][nt][i] = 0.0f;

    auto stageW = [&](int buf, int kc) {
        #pragma unroll
        for (int i = 0; i < 3; ++i) {
            int fp = tid + i * 512;            // 0..1535
            int r = fp >> 3, pb = fp & 7, g = pb ^ (r & 7);
            const u32 __attribute__((address_space(1)))* gsrc =
                (const u32 __attribute__((address_space(1)))*)
                    (Wt + (size_t)r * CC + kc * 64 + g * 8);
            u32 __attribute__((address_space(3)))* ldst =
                (u32 __attribute__((address_space(3)))*)(&Ws[buf][fp * 8]);
            __builtin_amdgcn_global_load_lds(gsrc, ldst, 16, 0, 0);
        }
    };
    auto loadX = [&](int set, int kc) {
        xa[set] = *(const float4*)(xsrc + kc * 64);
        xb[set] = *(const float4*)(xsrc + kc * 64 + 4);
    };
    auto writeX = [&](int set, int buf) {
        unsigned short h[8];
        h[0]=f2bf(xa[set].x); h[1]=f2bf(xa[set].y);
        h[2]=f2bf(xa[set].z); h[3]=f2bf(xa[set].w);
        h[4]=f2bf(xb[set].x); h[5]=f2bf(xb[set].y);
        h[6]=f2bf(xb[set].z); h[7]=f2bf(xb[set].w);
        *(us8*)&Xs[buf][xdst] = *(const us8*)h;
    };

    stageW(0, 0);
    loadX(0, 0); loadX(1, 1);
    writeX(0, 0);

    for (int kc = 0; kc < 16; ++kc) {
        int cur = kc & 1;
        if (kc < 15) asm volatile("s_waitcnt vmcnt(2) lgkmcnt(0)" ::: "memory");
        else         asm volatile("s_waitcnt vmcnt(0) lgkmcnt(0)" ::: "memory");
        __builtin_amdgcn_sched_barrier(0);
        __builtin_amdgcn_s_barrier();        // all waves' buf[cur] now valid
        if (kc < 15) stageW(1 - cur, kc + 1);
        if (kc < 14) loadX(kc & 1, kc + 2);
        #pragma unroll
        for (int ks = 0; ks < 2; ++ks) {
            int g = ks * 4 + quad;
            bf16x8 a[2], b[3];
            #pragma unroll
            for (int mt = 0; mt < 2; ++mt) {
                int arow = mg * 32 + mt * 16 + lq;
                a[mt] = *(const bf16x8*)&Xs[cur][arow * 64 + (g ^ (lq & 7)) * 8];
            }
            #pragma unroll
            for (int nt = 0; nt < 3; ++nt) {
                int brow = ng * 48 + nt * 16 + lq;
                b[nt] = *(const bf16x8*)&Ws[cur][brow * 64 + (g ^ (lq & 7)) * 8];
            }
            #pragma unroll
            for (int mt = 0; mt < 2; ++mt)
                #pragma unroll
                for (int nt = 0; nt < 3; ++nt)
                    acc[mt][nt] = __builtin_amdgcn_mfma_f32_16x16x32_bf16(
                        a[mt], b[nt], acc[mt][nt], 0, 0, 0);
        }
        if (kc < 15) writeX((kc + 1) & 1, 1 - cur);  // X[kc+1]
    }

    // epilogue: direct q|k|v writes (wave-uniform column buckets).
    int bidx = r0 >> 11;                       // batch
    int t0base = r0 & (TT - 1);
    #pragma unroll
    for (int mt = 0; mt < 2; ++mt) {
        #pragma unroll
        for (int nt = 0; nt < 3; ++nt) {
            int gcol = ng * 48 + nt * 16 + lq;
            int rloc = mg * 32 + mt * 16 + quad * 4;      // + i
            if (gcol < 64) {
                #pragma unroll
                for (int i = 0; i < 4; ++i)
                    qws[(size_t)(r0 + rloc + i) * HH + gcol] =
                        f2bf(acc[mt][nt][i]);
            } else if (gcol < 128) {
                #pragma unroll
                for (int i = 0; i < 4; ++i)
                    kws[(size_t)(r0 + rloc + i) * HH + (gcol - 64)] =
                        f2bf(acc[mt][nt][i]);
            } else {
                unsigned short o[4];
                #pragma unroll
                for (int i = 0; i < 4; ++i) o[i] = f2bf(acc[mt][nt][i]);
                *(us4*)(vws + ((size_t)bidx * HH + (gcol - 128)) * TT
                            + t0base + rloc) = *(const us4*)o;
            }
        }
    }
}

// ---------------------------------------------------------------------------
// Kernel 2: causal attention — ROUND-6 CHANGE: 64-key chunks + NSPLIT=4.
// Halves grid-wide chunk iterations (8448->4224) and barrier count, halves
// the ones-MFMA (Lc) per key, halves Op partial traffic (16->8MB). Grid
// 32x4x8=1024 blocks, 4/CU co-resident (LDS 27.6KB). Masking only on the
// jc==ti diagonal chunk. T14 reg-prefetch kept; T5 setprio added around
// MFMA clusters (attn-proven +4-7%). Rows [.][72]=144B keep b128 16B
// alignment; stride-36-dword b128 reads are at the bank floor (verified).
// ---------------------------------------------------------------------------
__global__ __launch_bounds__(128, 2) void attn(
        const unsigned short* __restrict__ qws,
        const unsigned short* __restrict__ kws,
        const unsigned short* __restrict__ vws,
        unsigned short* __restrict__ Op, float* __restrict__ Lp) {
    __shared__ unsigned short Kt[64][72];   // [key][h]
    __shared__ unsigned short Vt[64][72];   // [h][key]
    __shared__ unsigned short Ps[64][72];   // [q][key], rows wave-private
    int ti = blockIdx.x;            // 64-row q tile, 0..31
    int s  = blockIdx.y;            // kv split 0..NSPLIT-1
    int b  = blockIdx.z;
    if (s > ti) return;             // chunk indices for this tile: 0..ti
    int tid = threadIdx.x, wv = tid >> 6, lane = tid & 63;
    int half = lane >> 5, l31 = lane & 31;

    bf16x8 qf[4];
    {
        const unsigned short* qp =
            qws + ((size_t)b * TT + ti * 64 + wv * 32 + l31) * HH + half * 8;
        #pragma unroll
        for (int ks = 0; ks < 4; ++ks) qf[ks] = *(const bf16x8*)(qp + ks * 16);
    }
    f32x16 O0, O1, Lc;
    #pragma unroll
    for (int i = 0; i < 16; ++i) { O0[i] = 0.f; O1[i] = 0.f; Lc[i] = 0.f; }
    bf16x8 ones;
    #pragma unroll
    for (int i = 0; i < 8; ++i) ones[i] = (short)0x3F80;

    // staging: 128 threads x 4 rounds x us8 for each of K (64 keys x 64 h)
    // and V (64 h x 64 keys, pre-transposed in vws)
    int sr = tid >> 3, sg = tid & 7;
    const unsigned short* ksrc0 = kws + ((size_t)b * TT + sr) * HH + sg * 8;
    const unsigned short* vsrc0 = vws + ((size_t)b * HH + sr) * TT + sg * 8;

    us8 rk[4], rv[4];                          // T14 prefetch registers
    auto loadKV = [&](int jc) {
        #pragma unroll
        for (int i = 0; i < 4; ++i)
            rk[i] = *(const us8*)(ksrc0 + (size_t)(jc * 64 + i * 16) * HH);
        #pragma unroll
        for (int i = 0; i < 4; ++i)
            rv[i] = *(const us8*)(vsrc0 + (size_t)(i * 16) * TT + jc * 64);
    };
    auto writeKV = [&]() {
        #pragma unroll
        for (int i = 0; i < 4; ++i) *(us8*)&Kt[sr + i * 16][sg * 8] = rk[i];
        #pragma unroll
        for (int i = 0; i < 4; ++i) *(us8*)&Vt[sr + i * 16][sg * 8] = rv[i];
    };

    loadKV(s);                                 // prologue prefetch
    for (int jc = s; jc <= ti; jc += NSPLIT) {
        __syncthreads();   // prior iter's K/V reads done before restage
        writeKV();
        if (jc + NSPLIT <= ti) loadKV(jc + NSPLIT);   // hide under compute
        __syncthreads();
        f32x16 S0, S1;
        #pragma unroll
        for (int i = 0; i < 16; ++i) { S0[i] = 0.f; S1[i] = 0.f; }
        __builtin_amdgcn_s_setprio(1);
        #pragma unroll
        for (int ks = 0; ks < 4; ++ks) {
            bf16x8 kf0 = *(const bf16x8*)&Kt[l31][ks * 16 + half * 8];
            bf16x8 kf1 = *(const bf16x8*)&Kt[32 + l31][ks * 16 + half * 8];
            S0 = __builtin_amdgcn_mfma_f32_32x32x16_bf16(qf[ks], kf0, S0, 0, 0, 0);
            S1 = __builtin_amdgcn_mfma_f32_32x32x16_bf16(qf[ks], kf1, S1, 0, 0, 0);
        }
        __builtin_amdgcn_s_setprio(0);
        bool diag = (jc == ti);    // only the diagonal chunk needs masking
        #pragma unroll
        for (int r = 0; r < 16; ++r) {
            int pat = (r & 3) + 8 * (r >> 2) + 4 * half;    // local q row in wave
            float p0 = __builtin_amdgcn_exp2f(S0[r]);
            float p1 = __builtin_amdgcn_exp2f(S1[r]);
            if (diag) {
                int rloc = wv * 32 + pat;      // q row within the 64-tile
                if (l31 > rloc)      p0 = 0.0f;
                if (32 + l31 > rloc) p1 = 0.0f;
            }
            Ps[wv * 32 + pat][l31]      = f2bf(p0);
            Ps[wv * 32 + pat][32 + l31] = f2bf(p1);
        }
        // no __syncthreads: each wave reads only its own 32 Ps rows
        __builtin_amdgcn_s_setprio(1);
        #pragma unroll
        for (int ks = 0; ks < 4; ++ks) {
            bf16x8 pa  = *(const bf16x8*)&Ps[wv * 32 + l31][ks * 16 + half * 8];
            bf16x8 vf0 = *(const bf16x8*)&Vt[l31][ks * 16 + half * 8];
            bf16x8 vf1 = *(const bf16x8*)&Vt[32 + l31][ks * 16 + half * 8];
            O0 = __builtin_amdgcn_mfma_f32_32x32x16_bf16(pa, vf0, O0, 0, 0, 0);
            O1 = __builtin_amdgcn_mfma_f32_32x32x16_bf16(pa, vf1, O1, 0, 0, 0);
            Lc = __builtin_amdgcn_mfma_f32_32x32x16_bf16(pa, ones, Lc, 0, 0, 0);
        }
        __builtin_amdgcn_s_setprio(0);
    }
    // deterministic per-split partial store (bf16)
    unsigned short* Ob =
        Op + (((size_t)s * BB + b) * TT + ti * 64 + wv * 32) * HH;
    #pragma unroll
    for (int r = 0; r < 16; ++r) {
        int pat = (r & 3) + 8 * (r >> 2) + 4 * half;
        Ob[(size_t)pat * HH + l31]      = f2bf(O0[r]);
        Ob[(size_t)pat * HH + 32 + l31] = f2bf(O1[r]);
    }
    if (l31 == 0) {
        #pragma unroll
        for (int r = 0; r < 16; ++r) {
            int pat = (r & 3) + 8 * (r >> 2) + 4 * half;
            Lp[((size_t)s * BB + b) * TT + ti * 64 + wv * 32 + pat] = Lc[r];
        }
    }
}

// ---------------------------------------------------------------------------
// Kernel 3: out = (sum_s Op[s]) / (sum_s Lp[s]) — ns updated for 64-key
// chunks + NSPLIT=4 (split s active iff s <= ti -> ns = min(ti+1, 4)).
// ---------------------------------------------------------------------------
__global__ __launch_bounds__(256) void norm_out(
        const unsigned short* __restrict__ Op, const float* __restrict__ Lp,
        float* __restrict__ out) {
    int idx = blockIdx.x * 256 + threadIdx.x;     // 65536 total
    int g = idx >> 2;                             // global row b*T + t, <16384
    int hseg = (idx & 3) * 16;
    int ti = (g & (TT - 1)) >> 6;
    int ns = min(ti + 1, NSPLIT);
    float a[16];
    #pragma unroll
    for (int j = 0; j < 16; ++j) a[j] = 0.f;
    float Ls = 0.f;
    for (int s = 0; s < ns; ++s) {
        const unsigned short* base =
            Op + ((size_t)s * BB * TT + g) * HH + hseg;
        us8 u0 = *(const us8*)base;
        us8 u1 = *(const us8*)(base + 8);
        #pragma unroll
        for (int j = 0; j < 8; ++j) { a[j] += bf2f(u0[j]); a[8 + j] += bf2f(u1[j]); }
        Ls += Lp[(size_t)s * BB * TT + g];
    }
    float inv = 1.0f / Ls;
    float* ob = out + (size_t)g * HH + hseg;
    #pragma unroll
    for (int q = 0; q < 4; ++q) {
        float4 v = make_float4(a[q*4] * inv, a[q*4+1] * inv,
                               a[q*4+2] * inv, a[q*4+3] * inv);
        ((float4*)ob)[q] = v;
    }
}

// ---------------------------------------------------------------------------
extern "C" void kernel_launch(void* const* d_in, const int* in_sizes, int n_in,
                              void* d_out, int out_size, void* d_ws, size_t ws_size,
                              hipStream_t stream) {
    (void)in_sizes; (void)n_in; (void)out_size; (void)ws_size;
    const float* x  = (const float*)d_in[0];
    const float* Wq = (const float*)d_in[1];
    const float* Wk = (const float*)d_in[2];
    const float* Wv = (const float*)d_in[3];
    float* out = (float*)d_out;

    char* ws = (char*)d_ws;
    unsigned short* Wt  = (unsigned short*)ws;                          // 384 KB
    unsigned short* qws = (unsigned short*)(ws + (1u << 19));           // 2 MB
    unsigned short* kws = (unsigned short*)(ws + (1u << 19) + (1u << 21));
    unsigned short* vws = (unsigned short*)(ws + (1u << 19) + (2u << 21));
    unsigned short* Op  = (unsigned short*)(ws + (1u << 19) + (3u << 21)); // 8 MB bf16 (4 splits)
    float*          Lp  = (float*)(ws + (1u << 19) + (3u << 21) + (1u << 24)); // 256 KB

    prep_weights<<<48, 256, 0, stream>>>(Wq, Wk, Wv, Wt);
    proj_qkv<<<256, 512, 0, stream>>>(x, Wt, qws, kws, vws);
    attn<<<dim3(32, NSPLIT, 8), 128, 0, stream>>>(qws, kws, vws, Op, Lp);
    norm_out<<<256, 256, 0, stream>>>(Op, Lp, out);
}